// Round 1
// 581.056 us; speedup vs baseline: 1.0362x; 1.0362x over previous
//
#include <hip/hip_runtime.h>
#include <hip/hip_bf16.h>

// ---------------------------------------------------------------------------
// GLIF3 RSNN. KEY INSIGHT (R2): network is provably silent for these inputs,
// so spikes/psc/filtered == 0 exactly, output == b_out, and voltage is a
// linear EMA of I_ext.
//
// R3 structural insight: EMA and GEMM commute.
//   v_t = -60 + 0.05*scale*(y_t @ W_in^T),  y_t = 0.95*y_{t-1} + x_t.
// So we prefilter x in TIME first (cheap: 33 MB read, 65 MB bf16 write),
// then one bf16 MFMA GEMM writes volt DIRECTLY. This deletes the 131 MB f32
// Iext intermediate write and the 216 MB scan read of the R2 structure.
// Safety: GEMM epilogue checks computed v > -46 (1 V margin >> ~0.02 err)
// over every (t,b,n); full-dynamics fallback recomputes I_ext inline from
// x/W_in and runs only if flagged (never, for these inputs). Poison 0xAA..
// in the flag decodes to a negative float => silent path.
// ---------------------------------------------------------------------------

#define T_ 1000
#define B_ 64
#define D_ 128
#define N_ 512
#define O_ 10
#define BN_ (B_ * N_)                    // 32768
#define BD_ (B_ * D_)                    // 8192
#define S_ ((size_t)T_ * BN_)            // 32,768,000 elems per big output

typedef __bf16 bf16x8 __attribute__((ext_vector_type(8)));
typedef float f32x4 __attribute__((ext_vector_type(4)));

// ---------------- K0: temporal EMA prefilter, f32 -> bf16 -------------------
// y_t = 0.95*y_{t-1} + x_t (y_{-1}=0). Chunked over T with 128-step warmup
// (0.95^128 ~ 1.4e-3; y<=20 => truncation <0.03 in y => <0.002 in v).
// Thread q = (b,d) flat index: loads are 256B/wave coalesced, stores 128B.
#define PCH_ 50
#define PWARM_ 128
__global__ __launch_bounds__(256) void k_prefilter(
    const float* __restrict__ x, __bf16* __restrict__ yf,
    const float* __restrict__ bout, float* __restrict__ out)
{
  if (blockIdx.y == 0 && blockIdx.x == 0) {
    for (int i = threadIdx.x; i < B_ * O_; i += 256) out[i] = bout[i % O_];
  }
  const int q = blockIdx.x * 256 + threadIdx.x;   // 0..8191
  const int t0 = blockIdx.y * PCH_;
  int tw = t0 - PWARM_; if (tw < 0) tw = 0;
  float y = 0.f;
#pragma unroll 4
  for (int t = tw; t < t0; ++t) y = 0.95f * y + x[(size_t)t * BD_ + q];
#pragma unroll 5
  for (int t = t0; t < t0 + PCH_; ++t) {
    y = 0.95f * y + x[(size_t)t * BD_ + q];
    yf[(size_t)t * BD_ + q] = (__bf16)y;
  }
}

// ---------------- K1: volt GEMM (bf16 MFMA) + danger flag -------------------
// volt[m][n] = -60 + (0.05*scale) * sum_k yf[m][k] * W_in[n][k]; m = t*B+b.
// Grid: (500 row-tiles of 128, 2 col-halves of 256). 512 thr = 8 waves.
// W_in half staged in LDS as bf16, XOR-swizzled (64 KB, max 2-way conflict).
// A-operand is already bf16 (yf) -> direct 16B loads, no convert.
__global__ __launch_bounds__(512, 1) void k_gemm_volt(
    const __bf16* __restrict__ yf, const float* __restrict__ Win,
    const float* __restrict__ scale_p, float* __restrict__ volt,
    int* __restrict__ flagmax)
{
  __shared__ __bf16 sW[256 * 128];   // 64 KB
  const int tid = threadIdx.x;
  const int nbase = blockIdx.y * 256;
  const float cs = 0.05f * (*scale_p);

  for (int i = tid; i < 256 * 16; i += 512) {
    const int n = i >> 4, j = i & 15;
    const float4* src = (const float4*)(Win + (size_t)(nbase + n) * 128 + j * 8);
    float4 f0 = src[0], f1 = src[1];
    bf16x8 h;
    h[0] = (__bf16)f0.x; h[1] = (__bf16)f0.y; h[2] = (__bf16)f0.z; h[3] = (__bf16)f0.w;
    h[4] = (__bf16)f1.x; h[5] = (__bf16)f1.y; h[6] = (__bf16)f1.z; h[7] = (__bf16)f1.w;
    *(bf16x8*)(&sW[n * 128 + ((j ^ (n & 15)) << 3)]) = h;
  }
  __syncthreads();

  const int wave = tid >> 6, lane = tid & 63;
  const int quad = lane >> 4, l16 = lane & 15;
  const int mA = blockIdx.x * 128 + wave * 16 + l16;   // A-frag row (m = lane&15)

  f32x4 acc[16];
#pragma unroll
  for (int c = 0; c < 16; ++c) acc[c] = (f32x4){0.f, 0.f, 0.f, 0.f};

#pragma unroll
  for (int kb = 0; kb < 4; ++kb) {
    bf16x8 af = *(const bf16x8*)(yf + (size_t)mA * 128 + kb * 32 + quad * 8);
    const int j = kb * 4 + quad;   // k-octet index 0..15
#pragma unroll
    for (int c = 0; c < 16; ++c) {
      const int n = c * 16 + l16;  // B-frag col (n = lane&15)
      bf16x8 bfr = *(const bf16x8*)(&sW[n * 128 + ((j ^ (n & 15)) << 3)]);
      acc[c] = __builtin_amdgcn_mfma_f32_16x16x32_bf16(af, bfr, acc[c], 0, 0, 0);
    }
  }

  // epilogue: C/D layout col=lane&15, row=quad*4+reg; apply affine, flag max v
  float mx = -1e30f;
  const int mBase = blockIdx.x * 128 + wave * 16 + quad * 4;
#pragma unroll
  for (int c = 0; c < 16; ++c) {
#pragma unroll
    for (int r = 0; r < 4; ++r) {
      float vv = -60.f + cs * acc[c][r];
      mx = fmaxf(mx, vv);
      volt[(size_t)(mBase + r) * N_ + nbase + c * 16 + l16] = vv;
    }
  }
  if (flagmax) {
    for (int off = 32; off; off >>= 1) mx = fmaxf(mx, __shfl_xor(mx, off));
    if (lane == 0 && mx > -46.0f)               // spike threshold -45, 1V margin
      atomicMax(flagmax, __float_as_int(100.0f));
  }
}

// ---------------- K2: full-dynamics fallback (runs only if flagged) ---------
// Recomputes I_ext inline from x/W_in (no Iext buffer exists anymore).
__global__ __launch_bounds__(512) void k_fallback(
    const float* __restrict__ x, const float* __restrict__ Win,
    const float* __restrict__ iscale, const float* __restrict__ Wrec,
    const float* __restrict__ Wout, const float* __restrict__ bout,
    const float* __restrict__ osc_p,
    float* out, float* spikes, float* volt, float* psc_o, float* filt,
    const int* __restrict__ flagmax)
{
  if (!(__int_as_float(*flagmax) > 14.0f)) return;  // poison 0xAA.. < 0 => exit
  const int b = blockIdx.x, n = threadIdx.x;
  __shared__ float s_sp[N_];
  __shared__ float sx[D_];
  __shared__ float red[N_];
  const float sc = *iscale;
  const float e_syn = expf(-0.2f), e_asc = expf(-1.0f / 700.0f), alpha = expf(-0.05f);
  float v = -60.f, asc = 0.f, rr = 0.f, psc = 0.f, f = 0.f, favg = 0.f, sprev = 0.f;
  int refc = 0;
  for (int t = 0; t < T_; ++t) {
    s_sp[n] = sprev;
    if (n < D_) sx[n] = x[((size_t)t * B_ + b) * D_ + n];
    int cnt = __syncthreads_count(sprev > 0.f);
    float Iin = 0.f;
    for (int d = 0; d < D_; ++d) Iin += sx[d] * Win[(size_t)n * D_ + d];
    Iin *= sc;
    float rec = 0.f;
    if (cnt > 0)
      for (int m = 0; m < N_; ++m) rec += s_sp[m] * Wrec[(size_t)n * N_ + m];
    rr = rr * e_syn + rec;
    psc = psc * e_syn + 0.2f * rr;
    float I = Iin + psc + asc;
    v = (v + 0.05f * (-60.f - v)) + 0.05f * I;
    bool in_ref = refc > 0;
    if (in_ref) v = -60.f;
    float s = (!in_ref && (v - (-45.f) >= 0.f)) ? 1.f : 0.f;
    v = v * (1.f - s) + (-60.f) * s;
    refc = (s > 0.f) ? 5 : (refc > 0 ? refc - 1 : 0);
    asc = asc * e_asc + (-0.2f) * s;
    const size_t idx = (size_t)t * BN_ + (size_t)b * N_ + n;
    spikes[idx] = s; volt[idx] = v; psc_o[idx] = psc;
    f = (t == 0) ? s : (alpha * f + (1.f - alpha) * s);
    filt[idx] = f;
    if (t >= 200) favg += f;
    sprev = s;
    __syncthreads();
  }
  favg = favg / 800.f;
  float a_s = favg * (*osc_p);
  for (int o = 0; o < O_; ++o) {
    red[n] = a_s * Wout[o * N_ + n];
    __syncthreads();
    for (int st = 256; st; st >>= 1) {
      if (n < st) red[n] += red[n + st];
      __syncthreads();
    }
    if (n == 0) out[b * O_ + o] = red[0] + bout[o];
    __syncthreads();
  }
}

extern "C" void kernel_launch(void* const* d_in, const int* in_sizes, int n_in,
                              void* d_out, int out_size, void* d_ws, size_t ws_size,
                              hipStream_t stream) {
  const float* x      = (const float*)d_in[0];
  const float* Win    = (const float*)d_in[1];
  const float* iscale = (const float*)d_in[2];
  const float* Wrec   = (const float*)d_in[3];
  const float* Wout   = (const float*)d_in[4];
  const float* bout   = (const float*)d_in[5];
  const float* oscale = (const float*)d_in[6];

  float* out    = (float*)d_out;
  float* spikes = out + B_ * O_;
  float* volt   = spikes + S_;
  float* psc    = volt + S_;
  float* filt   = psc + S_;

  const bool has_flag = ws_size >= 4;
  int* flag = has_flag ? (int*)d_ws : nullptr;   // poison 0xAA.. reads as <0
  const bool ws_yf = ws_size >= (size_t)256 + S_ * 2;  // bf16 y buffer
  __bf16* yf = ws_yf ? (__bf16*)((char*)d_ws + 256) : (__bf16*)filt;

  // zero the identically-zero outputs via the fast fill path
  hipMemsetAsync(spikes, 0, S_ * 4, stream);                   // spikes
  hipMemsetAsync(psc, 0, (ws_yf ? 2 * S_ : S_) * 4, stream);   // psc (+filt)

  k_prefilter<<<dim3(32, 20), 256, 0, stream>>>(x, yf, bout, out);

  k_gemm_volt<<<dim3(500, 2), 512, 0, stream>>>(yf, Win, iscale, volt, flag);

  if (!ws_yf)  // yf lived in filt: zero it after the GEMM consumed it
    hipMemsetAsync(filt, 0, S_ * 4, stream);

  if (has_flag)
    k_fallback<<<64, 512, 0, stream>>>(x, Win, iscale, Wrec, Wout, bout, oscale,
                                       out, spikes, volt, psc, filt, flag);
}

// Round 2
// 575.104 us; speedup vs baseline: 1.0469x; 1.0103x over previous
//
#include <hip/hip_runtime.h>
#include <hip/hip_bf16.h>

// ---------------------------------------------------------------------------
// GLIF3 RSNN. KEY INSIGHT (R2): network is provably silent for these inputs,
// so spikes/psc/filtered == 0 exactly, output == b_out, and voltage is a
// linear EMA of I_ext.
//
// R3: EMA and GEMM commute: v_t = -60 + 0.05*scale*(y_t @ W_in^T),
//     y_t = 0.95*y_{t-1} + x_t.  Prefilter x in time (bf16 y), one MFMA GEMM
//     writes volt directly.
// R4: zero-fills (spikes 131MB, psc+filt 262MB) folded into the two compute
//     kernels as role-split blocks -> the streaming zero stores overlap the
//     prefilter's latency-bound warmup and the GEMM's MFMA/LDS phases instead
//     of serializing as standalone fill dispatches. 2 fewer graph nodes.
// Safety: GEMM epilogue checks computed v > -46 (1 V margin >> ~0.02 err)
// over every (t,b,n); full-dynamics fallback recomputes I_ext inline and
// runs only if flagged (never, for these inputs). Poison 0xAA.. in the flag
// decodes to a negative float => silent path.
// ---------------------------------------------------------------------------

#define T_ 1000
#define B_ 64
#define D_ 128
#define N_ 512
#define O_ 10
#define BN_ (B_ * N_)                    // 32768
#define BD_ (B_ * D_)                    // 8192
#define S_ ((size_t)T_ * BN_)            // 32,768,000 elems per big output

typedef __bf16 bf16x8 __attribute__((ext_vector_type(8)));
typedef float f32x4 __attribute__((ext_vector_type(4)));

// ---------------- K0: temporal EMA prefilter + psc/filt zeroing -------------
// y_t = 0.95*y_{t-1} + x_t (y_{-1}=0). Chunked over T with 128-step warmup
// (0.95^128 ~ 1.4e-3; y<=20 => truncation <0.03 in y => <0.002 in v).
// blockIdx.x < 32: prefilter (thread q=(b,d)); >=32: zero-role blocks
// streaming float4 zeros over zbase[0 .. z4*4).
#define PCH_ 50
#define PWARM_ 128
#define PZB_ 16                          // extra x-blocks for zero role
__global__ __launch_bounds__(256) void k_prefilter(
    const float* __restrict__ x, __bf16* __restrict__ yf,
    const float* __restrict__ bout, float* __restrict__ out,
    float* __restrict__ zbase, size_t z4)
{
  if (blockIdx.x >= 32) {                // zero role: 320 blocks
    const int zb = (blockIdx.x - 32) + PZB_ * blockIdx.y;   // 0..319
    float4* p = (float4*)zbase;
    const float4 z = make_float4(0.f, 0.f, 0.f, 0.f);
    for (size_t i = (size_t)zb * 256 + threadIdx.x; i < z4; i += (size_t)PZB_ * 20 * 256)
      p[i] = z;
    return;
  }
  if (blockIdx.y == 0 && blockIdx.x == 0) {
    for (int i = threadIdx.x; i < B_ * O_; i += 256) out[i] = bout[i % O_];
  }
  const int q = blockIdx.x * 256 + threadIdx.x;   // 0..8191
  const int t0 = blockIdx.y * PCH_;
  int tw = t0 - PWARM_; if (tw < 0) tw = 0;
  float y = 0.f;
#pragma unroll 4
  for (int t = tw; t < t0; ++t) y = 0.95f * y + x[(size_t)t * BD_ + q];
#pragma unroll 5
  for (int t = t0; t < t0 + PCH_; ++t) {
    y = 0.95f * y + x[(size_t)t * BD_ + q];
    yf[(size_t)t * BD_ + q] = (__bf16)y;
  }
}

// ---------------- K1: volt GEMM (bf16 MFMA) + danger flag + spikes zero -----
// volt[m][n] = -60 + (0.05*scale) * sum_k yf[m][k] * W_in[n][k]; m = t*B+b.
// Grid: (500+64 x, 2 y). x<500: compute tile (128 rows x 256 cols, 8 waves,
// W_in half in LDS bf16 XOR-swizzled). x>=500: 128 zero-role blocks
// streaming float4 zeros over spikes (131 MB) concurrent with the GEMM.
#define GZB_ 64
__global__ __launch_bounds__(512, 1) void k_gemm_volt(
    const __bf16* __restrict__ yf, const float* __restrict__ Win,
    const float* __restrict__ scale_p, float* __restrict__ volt,
    float* __restrict__ spikes, int* __restrict__ flagmax)
{
  if (blockIdx.x >= 500) {               // zero role: 128 blocks
    const int zb = (blockIdx.x - 500) + GZB_ * blockIdx.y;  // 0..127
    float4* p = (float4*)spikes;
    const float4 z = make_float4(0.f, 0.f, 0.f, 0.f);
    const size_t z4 = S_ / 4;            // 8,192,000
    for (size_t i = (size_t)zb * 512 + threadIdx.x; i < z4; i += (size_t)2 * GZB_ * 512)
      p[i] = z;
    return;
  }
  __shared__ __bf16 sW[256 * 128];   // 64 KB
  const int tid = threadIdx.x;
  const int nbase = blockIdx.y * 256;
  const float cs = 0.05f * (*scale_p);

  for (int i = tid; i < 256 * 16; i += 512) {
    const int n = i >> 4, j = i & 15;
    const float4* src = (const float4*)(Win + (size_t)(nbase + n) * 128 + j * 8);
    float4 f0 = src[0], f1 = src[1];
    bf16x8 h;
    h[0] = (__bf16)f0.x; h[1] = (__bf16)f0.y; h[2] = (__bf16)f0.z; h[3] = (__bf16)f0.w;
    h[4] = (__bf16)f1.x; h[5] = (__bf16)f1.y; h[6] = (__bf16)f1.z; h[7] = (__bf16)f1.w;
    *(bf16x8*)(&sW[n * 128 + ((j ^ (n & 15)) << 3)]) = h;
  }
  __syncthreads();

  const int wave = tid >> 6, lane = tid & 63;
  const int quad = lane >> 4, l16 = lane & 15;
  const int mA = blockIdx.x * 128 + wave * 16 + l16;   // A-frag row (m = lane&15)

  f32x4 acc[16];
#pragma unroll
  for (int c = 0; c < 16; ++c) acc[c] = (f32x4){0.f, 0.f, 0.f, 0.f};

#pragma unroll
  for (int kb = 0; kb < 4; ++kb) {
    bf16x8 af = *(const bf16x8*)(yf + (size_t)mA * 128 + kb * 32 + quad * 8);
    const int j = kb * 4 + quad;   // k-octet index 0..15
#pragma unroll
    for (int c = 0; c < 16; ++c) {
      const int n = c * 16 + l16;  // B-frag col (n = lane&15)
      bf16x8 bfr = *(const bf16x8*)(&sW[n * 128 + ((j ^ (n & 15)) << 3)]);
      acc[c] = __builtin_amdgcn_mfma_f32_16x16x32_bf16(af, bfr, acc[c], 0, 0, 0);
    }
  }

  // epilogue: C/D layout col=lane&15, row=quad*4+reg; apply affine, flag max v
  float mx = -1e30f;
  const int mBase = blockIdx.x * 128 + wave * 16 + quad * 4;
#pragma unroll
  for (int c = 0; c < 16; ++c) {
#pragma unroll
    for (int r = 0; r < 4; ++r) {
      float vv = -60.f + cs * acc[c][r];
      mx = fmaxf(mx, vv);
      volt[(size_t)(mBase + r) * N_ + nbase + c * 16 + l16] = vv;
    }
  }
  if (flagmax) {
    for (int off = 32; off; off >>= 1) mx = fmaxf(mx, __shfl_xor(mx, off));
    if (lane == 0 && mx > -46.0f)               // spike threshold -45, 1V margin
      atomicMax(flagmax, __float_as_int(100.0f));
  }
}

// ---------------- K2: full-dynamics fallback (runs only if flagged) ---------
// Recomputes I_ext inline from x/W_in (no Iext buffer exists anymore).
__global__ __launch_bounds__(512) void k_fallback(
    const float* __restrict__ x, const float* __restrict__ Win,
    const float* __restrict__ iscale, const float* __restrict__ Wrec,
    const float* __restrict__ Wout, const float* __restrict__ bout,
    const float* __restrict__ osc_p,
    float* out, float* spikes, float* volt, float* psc_o, float* filt,
    const int* __restrict__ flagmax)
{
  if (!(__int_as_float(*flagmax) > 14.0f)) return;  // poison 0xAA.. < 0 => exit
  const int b = blockIdx.x, n = threadIdx.x;
  __shared__ float s_sp[N_];
  __shared__ float sx[D_];
  __shared__ float red[N_];
  const float sc = *iscale;
  const float e_syn = expf(-0.2f), e_asc = expf(-1.0f / 700.0f), alpha = expf(-0.05f);
  float v = -60.f, asc = 0.f, rr = 0.f, psc = 0.f, f = 0.f, favg = 0.f, sprev = 0.f;
  int refc = 0;
  for (int t = 0; t < T_; ++t) {
    s_sp[n] = sprev;
    if (n < D_) sx[n] = x[((size_t)t * B_ + b) * D_ + n];
    int cnt = __syncthreads_count(sprev > 0.f);
    float Iin = 0.f;
    for (int d = 0; d < D_; ++d) Iin += sx[d] * Win[(size_t)n * D_ + d];
    Iin *= sc;
    float rec = 0.f;
    if (cnt > 0)
      for (int m = 0; m < N_; ++m) rec += s_sp[m] * Wrec[(size_t)n * N_ + m];
    rr = rr * e_syn + rec;
    psc = psc * e_syn + 0.2f * rr;
    float I = Iin + psc + asc;
    v = (v + 0.05f * (-60.f - v)) + 0.05f * I;
    bool in_ref = refc > 0;
    if (in_ref) v = -60.f;
    float s = (!in_ref && (v - (-45.f) >= 0.f)) ? 1.f : 0.f;
    v = v * (1.f - s) + (-60.f) * s;
    refc = (s > 0.f) ? 5 : (refc > 0 ? refc - 1 : 0);
    asc = asc * e_asc + (-0.2f) * s;
    const size_t idx = (size_t)t * BN_ + (size_t)b * N_ + n;
    spikes[idx] = s; volt[idx] = v; psc_o[idx] = psc;
    f = (t == 0) ? s : (alpha * f + (1.f - alpha) * s);
    filt[idx] = f;
    if (t >= 200) favg += f;
    sprev = s;
    __syncthreads();
  }
  favg = favg / 800.f;
  float a_s = favg * (*osc_p);
  for (int o = 0; o < O_; ++o) {
    red[n] = a_s * Wout[o * N_ + n];
    __syncthreads();
    for (int st = 256; st; st >>= 1) {
      if (n < st) red[n] += red[n + st];
      __syncthreads();
    }
    if (n == 0) out[b * O_ + o] = red[0] + bout[o];
    __syncthreads();
  }
}

extern "C" void kernel_launch(void* const* d_in, const int* in_sizes, int n_in,
                              void* d_out, int out_size, void* d_ws, size_t ws_size,
                              hipStream_t stream) {
  const float* x      = (const float*)d_in[0];
  const float* Win    = (const float*)d_in[1];
  const float* iscale = (const float*)d_in[2];
  const float* Wrec   = (const float*)d_in[3];
  const float* Wout   = (const float*)d_in[4];
  const float* bout   = (const float*)d_in[5];
  const float* oscale = (const float*)d_in[6];

  float* out    = (float*)d_out;
  float* spikes = out + B_ * O_;
  float* volt   = spikes + S_;
  float* psc    = volt + S_;
  float* filt   = psc + S_;

  const bool has_flag = ws_size >= 4;
  int* flag = has_flag ? (int*)d_ws : nullptr;   // poison 0xAA.. reads as <0
  const bool ws_yf = ws_size >= (size_t)256 + S_ * 2;  // bf16 y buffer
  __bf16* yf = ws_yf ? (__bf16*)((char*)d_ws + 256) : (__bf16*)filt;

  // K0: prefilter + zero psc (and filt too, unless yf aliases filt)
  const size_t z4 = (ws_yf ? 2 * S_ : S_) / 4;   // float4 count at psc
  k_prefilter<<<dim3(32 + PZB_, 20), 256, 0, stream>>>(x, yf, bout, out, psc, z4);

  // K1: GEMM -> volt, + zero spikes via role blocks
  k_gemm_volt<<<dim3(500 + GZB_, 2), 512, 0, stream>>>(yf, Win, iscale, volt,
                                                       spikes, flag);

  if (!ws_yf)  // yf lived in filt: zero it after the GEMM consumed it
    hipMemsetAsync(filt, 0, S_ * 4, stream);

  if (has_flag)
    k_fallback<<<64, 512, 0, stream>>>(x, Win, iscale, Wrec, Wout, bout, oscale,
                                       out, spikes, volt, psc, filt, flag);
}